// Round 6
// baseline (231.380 us; speedup 1.0000x reference)
//
#include <hip/hip_runtime.h>

// GraphConvolution: out[b,n,o] = sum_m adj[n,m] * (F[b,m,:] . W[o,:]) + b[o]
// B=8192, N=4, DIN=1024, DOUT=256.
//
// R7: every version since R0 sits ~3x over the memory floor with ALL pipes
// <15% busy -> pure latency exposure. The remaining structural coupling is
// the per-kb barrier lockstep (16 barriers; every wave clamped to the
// slowest wave's HBM->f2bf->ds_write chain). Fix: per-wave-private A
// staging -- each wave stages all 32 A rows into its OWN LDS quadrant
// (4 waves x dbuf x 4.5 KB = 36 KB/block), so ds_write->ds_read is
// wave-local: ZERO barriers, zero inline asm, compiler free to pipeline,
// waves slide independently. A is loaded 4x per block (L1/L2 absorbs it:
// same 8 KB/kb read by 4 waves; worst case ~1.25 TB/s/XCD extra L2, fine).
// B keeps R6's coalesced MFMA-fragment W image (1-KB wave loads from L2).
// Epilogue & numerics unchanged (bit-identical to R6).

#define DIN 1024
#define DOUT 256
#define BM 32
#define KI 16                      // DIN / 64
#define LDB 72                     // sA padded row stride in bf16
#define A_HALFS (BM * LDB)         // 2304 ushorts per wave-buffer

typedef __bf16 bf16x8 __attribute__((ext_vector_type(8)));
typedef float f32x4 __attribute__((ext_vector_type(4)));
typedef unsigned short u16x8 __attribute__((ext_vector_type(8)));

__device__ __forceinline__ unsigned short f2bf(float f) {
  union { float f; unsigned int u; } v;
  v.f = f;
  unsigned int u = v.u;
  u += 0x7fffu + ((u >> 16) & 1u);   // round-to-nearest-even
  return (unsigned short)(u >> 16);
}

__device__ __forceinline__ u16x8 pack8(f32x4 lo, f32x4 hi) {
  u16x8 r;
#pragma unroll
  for (int m = 0; m < 4; ++m) {
    r[m] = f2bf(lo[m]);
    r[4 + m] = f2bf(hi[m]);
  }
  return r;
}

// Pre-kernel: W [256x1024] fp32 -> bf16 in MFMA-fragment order (R6-verified).
// Chunk c = ((g*16 + kb)*2 + ks)*4 + j  (512 chunks x 1 KB = 512 KB);
// within a chunk, lane l holds W[g*64+j*16+(l&15)][kb*64+ks*32+(l>>4)*8..+8].
__global__ __launch_bounds__(256) void wprep_kernel(
    const float* __restrict__ W, unsigned short* __restrict__ ws) {
  const int t = blockIdx.x * 256 + threadIdx.x;  // 32768 threads, one bf16x8 each
  const int lane = t & 63;
  const int j = (t >> 6) & 3;
  const int ks = (t >> 8) & 1;
  const int kb = (t >> 9) & 15;
  const int g = (t >> 13) & 3;
  const int col = g * 64 + j * 16 + (lane & 15);
  const int k0 = kb * 64 + ks * 32 + (lane >> 4) * 8;
  const f32x4* src = (const f32x4*)(W + (size_t)col * DIN + k0);
  f32x4 a = src[0], b = src[1];
  *(u16x8*)(ws + (size_t)t * 8) = pack8(a, b);
}

__global__ __launch_bounds__(256, 3) void gconv_kernel(
    const float* __restrict__ adj, const float* __restrict__ feat,
    const unsigned short* __restrict__ wbf, const float* __restrict__ bias,
    float* __restrict__ out) {
  // [wave][dbuf][row*LDB + k] -- 4 x 2 x 4.5 KB = 36 KB
  __shared__ __align__(16) unsigned short sA[4][2][A_HALFS];

  const int tid = threadIdx.x;
  const int bM = blockIdx.x * BM;

  const int lane = tid & 63;
  const int wid = tid >> 6;
  const int wc = wid * 64;
  const int rl = lane & 15;
  const int q = lane >> 4;
  const int q8 = q * 8;

  // per-wave A staging: pair v covers rows 8v..8v+7; lane l -> row 8v+(l>>3),
  // float-chunk (l&7)*8 of the current 64-float K-block.
  const int arow = lane >> 3;        // 0..7
  const int ac8 = (lane & 7) * 8;    // 0..56
  const float* abase = feat + (size_t)(bM + arow) * DIN + ac8;
  unsigned short* swl = &sA[wid][0][arow * LDB + ac8];

  // fragment-ordered B: wave 'wid' owns chunks [wid*128 .. wid*128+127]
  const unsigned short* bp = wbf + (size_t)wid * 128 * 512 + lane * 8;

  f32x4 acc[2][4];
#pragma unroll
  for (int i = 0; i < 2; ++i)
#pragma unroll
    for (int j = 0; j < 4; ++j) acc[i][j] = f32x4{0.f, 0.f, 0.f, 0.f};

  // prologue: kb=0 -> regs -> bf16 -> own buf0; then prefetch kb=1 regs
  f32x4 pf[4][2];
#pragma unroll
  for (int v = 0; v < 4; ++v) {
    pf[v][0] = *(const f32x4*)(abase + (size_t)v * 8 * DIN);
    pf[v][1] = *(const f32x4*)(abase + (size_t)v * 8 * DIN + 4);
  }
#pragma unroll
  for (int v = 0; v < 4; ++v)
    *(u16x8*)(swl + v * 8 * LDB) = pack8(pf[v][0], pf[v][1]);
#pragma unroll
  for (int v = 0; v < 4; ++v) {
    pf[v][0] = *(const f32x4*)(abase + (size_t)v * 8 * DIN + 64);
    pf[v][1] = *(const f32x4*)(abase + (size_t)v * 8 * DIN + 68);
  }

  for (int kb = 0; kb < KI; ++kb) {
    // B fragments: coalesced 1-KB wave loads from the L2-resident image
    bf16x8 bfr[2][4];
#pragma unroll
    for (int ks = 0; ks < 2; ++ks)
#pragma unroll
      for (int j = 0; j < 4; ++j)
        bfr[ks][j] = *(const bf16x8*)(bp + ((kb * 2 + ks) * 4 + j) * 512);

    // A fragments from this wave's own buffer (wave-local lgkm ordering;
    // no barrier -- writer and reader are the same wave)
    const unsigned short* sa = &sA[wid][kb & 1][0];
    bf16x8 af[2][2];
#pragma unroll
    for (int i = 0; i < 2; ++i)
#pragma unroll
      for (int ks = 0; ks < 2; ++ks)
        af[i][ks] = *(const bf16x8*)(sa + (i * 16 + rl) * LDB + ks * 32 + q8);

#pragma unroll
    for (int ks = 0; ks < 2; ++ks)
#pragma unroll
      for (int i = 0; i < 2; ++i)
#pragma unroll
        for (int j = 0; j < 4; ++j)
          acc[i][j] = __builtin_amdgcn_mfma_f32_16x16x32_bf16(
              af[i][ks], bfr[ks][j], acc[i][j], 0, 0, 0);

    // stage next kb into the other private buffer; prefetch kb+2
    if (kb + 1 < KI) {
      unsigned short* sw = swl + ((kb + 1) & 1) * A_HALFS;
#pragma unroll
      for (int v = 0; v < 4; ++v)
        *(u16x8*)(sw + v * 8 * LDB) = pack8(pf[v][0], pf[v][1]);
      if (kb + 2 < KI) {
#pragma unroll
        for (int v = 0; v < 4; ++v) {
          pf[v][0] =
              *(const f32x4*)(abase + (size_t)v * 8 * DIN + (kb + 2) * 64);
          pf[v][1] =
              *(const f32x4*)(abase + (size_t)v * 8 * DIN + (kb + 2) * 64 + 4);
        }
      }
    }
  }

  // epilogue: adj 4x4 mix (regs = rows 4q..4q+3 of one batch) + bias
  float am[16];
#pragma unroll
  for (int i = 0; i < 16; ++i) am[i] = adj[i];  // uniform -> scalar loads

  float bv[4];
#pragma unroll
  for (int j = 0; j < 4; ++j) bv[j] = bias[wc + j * 16 + rl];

#pragma unroll
  for (int i = 0; i < 2; ++i) {
    const size_t rowbase = (size_t)(bM + i * 16 + q * 4);
#pragma unroll
    for (int j = 0; j < 4; ++j) {
      const int col = wc + j * 16 + rl;
      float* op = out + rowbase * DOUT + col;
      f32x4 g = acc[i][j];
#pragma unroll
      for (int n = 0; n < 4; ++n) {
        op[(size_t)n * DOUT] = am[n * 4 + 0] * g[0] + am[n * 4 + 1] * g[1] +
                               am[n * 4 + 2] * g[2] + am[n * 4 + 3] * g[3] +
                               bv[j];
      }
    }
  }
}

extern "C" void kernel_launch(void* const* d_in, const int* in_sizes, int n_in,
                              void* d_out, int out_size, void* d_ws,
                              size_t ws_size, hipStream_t stream) {
  const float* adj = (const float*)d_in[0];
  const float* feat = (const float*)d_in[1];
  const float* W = (const float*)d_in[2];
  const float* bias = (const float*)d_in[3];
  float* out = (float*)d_out;
  unsigned short* ws = (unsigned short*)d_ws;  // 512 KB fragment-ordered image

  wprep_kernel<<<128, 256, 0, stream>>>(W, ws);
  gconv_kernel<<<8192 * 4 / BM, 256, 0, stream>>>(adj, feat, ws, bias, out);
}